// Round 1
// baseline (398.926 us; speedup 1.0000x reference)
//
#include <hip/hip_runtime.h>
#include <cstdint>
#include <cstddef>

// Problem dims (B, D, F, T, H) = (256, 128, 8, 128, 128)
#define Bn 256
#define Dn 128
#define Fn 8
#define Tn 128
#define Hn 128
#define Kn 1024   // D*F
#define Mn 512    // 4*H
#define GXP 130   // padded pitch (f16 elems) for gates_x rows in LDS

typedef float f32x4 __attribute__((ext_vector_type(4)));
typedef short s16x8 __attribute__((ext_vector_type(8)));
typedef _Float16 h16x2 __attribute__((ext_vector_type(2)));

#if defined(__has_builtin)
#if __has_builtin(__builtin_amdgcn_fdot2)
#define HAVE_FDOT2 1
#else
#define HAVE_FDOT2 0
#endif
#else
#define HAVE_FDOT2 0
#endif

__device__ __forceinline__ unsigned short f32_to_bf16_rne(float f) {
  union { float f; uint32_t u; } v; v.f = f;
  uint32_t u = v.u;
  u += 0x7fffu + ((u >> 16) & 1u);
  return (unsigned short)(u >> 16);
}
__device__ __forceinline__ float bf16_to_f32(unsigned short h) {
  union { uint32_t u; float f; } v; v.u = ((uint32_t)h) << 16;
  return v.f;
}
__device__ __forceinline__ float sigm(float x) { return 1.0f / (1.0f + __expf(-x)); }
__device__ __forceinline__ float tanh_fast(float x) { return 1.0f - 2.0f / (__expf(2.0f * x) + 1.0f); }

// ---------------------------------------------------------------------------
// K1: ex[b,d] = input[b,d,:,:] . w_x ; a[b,:] = softmax_D(ex[b,:])
// (softmax is shift-invariant => the h/c/b_attn term cancels)
// ---------------------------------------------------------------------------
__global__ __launch_bounds__(256) void k_softmax_a(const float* __restrict__ input,
                                                   const float* __restrict__ w_attn,
                                                   float* __restrict__ a_out) {
  __shared__ float wx[Kn];
  __shared__ float exs[Dn];
  __shared__ float red[8];
  const int tid = threadIdx.x;
  const int b = blockIdx.x;
  ((float4*)wx)[tid] = ((const float4*)(w_attn + 2 * Hn))[tid];  // w_x = w_attn[256:1280]
  __syncthreads();
  const int w = tid >> 6, lane = tid & 63;
  const float4* wx4 = (const float4*)wx;
  for (int it = 0; it < 32; ++it) {
    const int d = it * 4 + w;
    const float4* xp = (const float4*)(input + ((size_t)b * Dn + d) * Kn);
    float acc = 0.f;
#pragma unroll
    for (int r = 0; r < 4; ++r) {
      float4 x = xp[lane + r * 64];
      float4 ww = wx4[lane + r * 64];
      acc += x.x * ww.x + x.y * ww.y + x.z * ww.z + x.w * ww.w;
    }
#pragma unroll
    for (int off = 32; off; off >>= 1) acc += __shfl_xor(acc, off);
    if (lane == 0) exs[d] = acc;
  }
  __syncthreads();
  float v = (tid < Dn) ? exs[tid] : -3.4e38f;
  float m = v;
#pragma unroll
  for (int off = 32; off; off >>= 1) m = fmaxf(m, __shfl_xor(m, off));
  if (lane == 0) red[w] = m;
  __syncthreads();
  m = fmaxf(fmaxf(red[0], red[1]), fmaxf(red[2], red[3]));
  float e = (tid < Dn) ? __expf(v - m) : 0.f;
  float s = e;
#pragma unroll
  for (int off = 32; off; off >>= 1) s += __shfl_xor(s, off);
  if (lane == 0) red[4 + w] = s;
  __syncthreads();
  s = red[4] + red[5] + red[6] + red[7];
  if (tid < Dn) a_out[b * Dn + tid] = e / s;
}

// ---------------------------------------------------------------------------
// K2: W_ih (512x1024 f32) -> hi/lo bf16 pair, pre-swizzled into MFMA A-frag
// order: dst[((mt*32+kt)*64+lane)*8 + j] = W[mt*16+(lane&15)][kt*32+(lane>>4)*8+j]
// ---------------------------------------------------------------------------
__global__ __launch_bounds__(256) void k_prep_wih(const float* __restrict__ W_ih,
                                                  unsigned short* __restrict__ whi,
                                                  unsigned short* __restrict__ wlo) {
  const int gid = blockIdx.x * 256 + threadIdx.x;  // 65536 groups of 8
  const int lane = gid & 63;
  const int kt = (gid >> 6) & 31;
  const int mt = gid >> 11;
  const int row = mt * 16 + (lane & 15);
  const int col = kt * 32 + (lane >> 4) * 8;
  const float* src = W_ih + row * Kn + col;
  unsigned short hi8[8], lo8[8];
#pragma unroll
  for (int j = 0; j < 8; ++j) {
    float wv = src[j];
    unsigned short h = f32_to_bf16_rne(wv);
    hi8[j] = h;
    lo8[j] = f32_to_bf16_rne(wv - bf16_to_f32(h));
  }
  uint4 ph, pl;
  ph.x = (uint32_t)hi8[0] | ((uint32_t)hi8[1] << 16);
  ph.y = (uint32_t)hi8[2] | ((uint32_t)hi8[3] << 16);
  ph.z = (uint32_t)hi8[4] | ((uint32_t)hi8[5] << 16);
  ph.w = (uint32_t)hi8[6] | ((uint32_t)hi8[7] << 16);
  pl.x = (uint32_t)lo8[0] | ((uint32_t)lo8[1] << 16);
  pl.y = (uint32_t)lo8[2] | ((uint32_t)lo8[3] << 16);
  pl.z = (uint32_t)lo8[4] | ((uint32_t)lo8[5] << 16);
  pl.w = (uint32_t)lo8[6] | ((uint32_t)lo8[7] << 16);
  ((uint4*)whi)[gid] = ph;
  ((uint4*)wlo)[gid] = pl;
}

// ---------------------------------------------------------------------------
// K3: per-batch fused  gates_x = W_ih @ (a*x)  (bf16 MFMA, W split hi/lo)
//     then 128-step LSTM recurrence, one block (8 waves) per batch.
// LDS: gates_x f16 [512][130] (133120 B, unioned with B-staging 16 KB)
// ---------------------------------------------------------------------------
#define SM_A    133120
#define SM_G    133632
#define SM_H2   135680
#define SM_H32  135936
#define SM_TOT  136512

__global__ __launch_bounds__(512, 2) void k_fused(
    const float* __restrict__ input, const float* __restrict__ a_in,
    const unsigned short* __restrict__ whi, const unsigned short* __restrict__ wlo,
    const float* __restrict__ W_hh, const float* __restrict__ b_ih,
    const float* __restrict__ b_hh, float* __restrict__ out) {
  __shared__ __align__(16) unsigned char smem[SM_TOT];
  _Float16* gx = (_Float16*)smem;                 // [512][GXP] f16 (after GEMM)
  unsigned short* bb = (unsigned short*)smem;     // B staging (aliases gx region)
  float* a_lds = (float*)(smem + SM_A);           // [128]
  float* gstep = (float*)(smem + SM_G);           // [512]
  _Float16* h2l = (_Float16*)(smem + SM_H2);      // [128] f16
  float* h32 = (float*)(smem + SM_H32);           // [128] f32

  const int tid = threadIdx.x;
  const int b = blockIdx.x;
  const int w = tid >> 6;
  const int lane = tid & 63;
  const int quad = lane >> 4;
  const int l15 = lane & 15;

  if (tid < Dn) a_lds[tid] = a_in[b * Dn + tid];

  f32x4 acc[4][8];
#pragma unroll
  for (int i = 0; i < 4; ++i)
#pragma unroll
    for (int j = 0; j < 8; ++j) {
      f32x4 z = {0.f, 0.f, 0.f, 0.f};
      acc[i][j] = z;
    }

  // staging map: thread -> column t (0..127) and k-chunk pair
  const int st_t = ((tid >> 6) & 1) * 64 + (tid & 63);  // 0..127
  const int kb2 = tid >> 7;                             // 0..3
  const float* xb = input + (size_t)b * Kn * Tn;

  __syncthreads();  // a_lds ready

  for (int kt = 0; kt < 16; ++kt) {  // K-tile = 64
    const int k0 = kt * 64;
    // ---- stage B tile: fp32 -> a-scaled bf16, fragment-order LDS chunks ----
#pragma unroll
    for (int hf = 0; hf < 2; ++hf) {
      const int kb = kb2 + hf * 4;  // 0..7
      const float av = a_lds[kt * 8 + kb];
      const float* col = xb + (size_t)(k0 + kb * 8) * Tn + st_t;
      unsigned short hx[8];
#pragma unroll
      for (int jj = 0; jj < 8; ++jj) hx[jj] = f32_to_bf16_rne(av * col[jj * Tn]);
      uint4 pk;
      pk.x = (uint32_t)hx[0] | ((uint32_t)hx[1] << 16);
      pk.y = (uint32_t)hx[2] | ((uint32_t)hx[3] << 16);
      pk.z = (uint32_t)hx[4] | ((uint32_t)hx[5] << 16);
      pk.w = (uint32_t)hx[6] | ((uint32_t)hx[7] << 16);
      ((uint4*)bb)[kb * 128 + st_t] = pk;
    }
    __syncthreads();
    // ---- MFMA: 2 k-frags x 4 m-tiles x 8 n-tiles x (hi,lo) ----
#pragma unroll
    for (int kf = 0; kf < 2; ++kf) {
      const int ktg = kt * 2 + kf;
      s16x8 afh[4], afl[4];
#pragma unroll
      for (int mt = 0; mt < 4; ++mt) {
        const int mtg = w * 4 + mt;
        const size_t fo = ((size_t)(mtg * 32 + ktg) * 64 + lane) * 8;
        afh[mt] = *(const s16x8*)(whi + fo);
        afl[mt] = *(const s16x8*)(wlo + fo);
      }
      s16x8 bfr[8];
#pragma unroll
      for (int nt = 0; nt < 8; ++nt) {
        const int chunk = (kf * 4 + quad) * 128 + nt * 16 + l15;
        bfr[nt] = *(const s16x8*)(bb + chunk * 8);
      }
#pragma unroll
      for (int mt = 0; mt < 4; ++mt)
#pragma unroll
        for (int nt = 0; nt < 8; ++nt) {
          acc[mt][nt] = __builtin_amdgcn_mfma_f32_16x16x32_bf16(afh[mt], bfr[nt], acc[mt][nt], 0, 0, 0);
          acc[mt][nt] = __builtin_amdgcn_mfma_f32_16x16x32_bf16(afl[mt], bfr[nt], acc[mt][nt], 0, 0, 0);
        }
    }
    __syncthreads();
  }

  // ---- epilogue: acc (C-layout row=quad*4+r, col=l15) -> gx f16 LDS ----
#pragma unroll
  for (int mt = 0; mt < 4; ++mt)
#pragma unroll
    for (int nt = 0; nt < 8; ++nt)
#pragma unroll
      for (int r = 0; r < 4; ++r) {
        const int j = w * 64 + mt * 16 + quad * 4 + r;
        const int t = nt * 16 + l15;
        gx[j * GXP + t] = (_Float16)acc[mt][nt][r];
      }

  // ---- load W_hh row j into regs, init state ----
  const int j = tid;
  const float bsum = b_ih[j] + b_hh[j];
#if HAVE_FDOT2
  h16x2 wreg[64];
  {
    const float2* wrow = (const float2*)(W_hh + (size_t)j * Hn);
#pragma unroll
    for (int kk = 0; kk < 64; ++kk) {
      float2 w2 = wrow[kk];
      h16x2 t2;
      t2.x = (_Float16)w2.x;
      t2.y = (_Float16)w2.y;
      wreg[kk] = t2;
    }
  }
#else
  float wreg[128];
  {
    const float4* wrow = (const float4*)(W_hh + (size_t)j * Hn);
#pragma unroll
    for (int kk = 0; kk < 32; ++kk) {
      float4 w4 = wrow[kk];
      wreg[kk * 4 + 0] = w4.x;
      wreg[kk * 4 + 1] = w4.y;
      wreg[kk * 4 + 2] = w4.z;
      wreg[kk * 4 + 3] = w4.w;
    }
  }
#endif
  if (tid < Dn) {
    h2l[tid] = (_Float16)0.f;
    h32[tid] = 0.f;
  }
  float c_st = 0.f;
  __syncthreads();

  float* outp = out + (size_t)b * Tn * Hn;
  for (int t = 0; t < Tn; ++t) {
    float a0 = bsum + (float)gx[j * GXP + t];
    float a1 = 0.f, a2 = 0.f, a3 = 0.f;
#if HAVE_FDOT2
    const h16x2* hc = (const h16x2*)h2l;
#pragma unroll
    for (int kk = 0; kk < 16; ++kk) {
      a0 = __builtin_amdgcn_fdot2(wreg[kk * 4 + 0], hc[kk * 4 + 0], a0, false);
      a1 = __builtin_amdgcn_fdot2(wreg[kk * 4 + 1], hc[kk * 4 + 1], a1, false);
      a2 = __builtin_amdgcn_fdot2(wreg[kk * 4 + 2], hc[kk * 4 + 2], a2, false);
      a3 = __builtin_amdgcn_fdot2(wreg[kk * 4 + 3], hc[kk * 4 + 3], a3, false);
    }
#else
    const float4* hc4 = (const float4*)h32;
#pragma unroll
    for (int kk = 0; kk < 32; ++kk) {
      float4 h4 = hc4[kk];
      a0 = fmaf(wreg[kk * 4 + 0], h4.x, a0);
      a1 = fmaf(wreg[kk * 4 + 1], h4.y, a1);
      a2 = fmaf(wreg[kk * 4 + 2], h4.z, a2);
      a3 = fmaf(wreg[kk * 4 + 3], h4.w, a3);
    }
#endif
    gstep[j] = a0 + a1 + a2 + a3;
    __syncthreads();
    if (tid < Hn) {
      const int d = tid;
      const float gi = gstep[d];
      const float gf = gstep[Hn + d];
      const float gg = gstep[2 * Hn + d];
      const float go = gstep[3 * Hn + d];
      c_st = sigm(gf) * c_st + sigm(gi) * tanh_fast(gg);
      const float hnew = sigm(go) * tanh_fast(c_st);
      outp[t * Hn + d] = hnew;
      h2l[d] = (_Float16)hnew;
      h32[d] = hnew;
    }
    __syncthreads();
  }
}

// ---------------------------------------------------------------------------
extern "C" void kernel_launch(void* const* d_in, const int* in_sizes, int n_in,
                              void* d_out, int out_size, void* d_ws, size_t ws_size,
                              hipStream_t stream) {
  (void)in_sizes; (void)n_in; (void)out_size; (void)ws_size;
  const float* input = (const float*)d_in[0];
  const float* w_attn = (const float*)d_in[1];
  // d_in[2] = b_attn: dead (softmax shift-invariance), as are w_h, w_c.
  const float* W_ih = (const float*)d_in[3];
  const float* W_hh = (const float*)d_in[4];
  const float* b_ih = (const float*)d_in[5];
  const float* b_hh = (const float*)d_in[6];
  float* out = (float*)d_out;

  float* a_ws = (float*)d_ws;                                            // 256*128*4 = 128 KB
  unsigned short* whi = (unsigned short*)((char*)d_ws + 131072);          // 1 MB
  unsigned short* wlo = (unsigned short*)((char*)d_ws + 131072 + 1048576);// 1 MB

  k_softmax_a<<<Bn, 256, 0, stream>>>(input, w_attn, a_ws);
  k_prep_wih<<<256, 256, 0, stream>>>(W_ih, whi, wlo);
  k_fused<<<Bn, 512, 0, stream>>>(input, a_ws, whi, wlo, W_hh, b_ih, b_hh, out);
}